// Round 8
// baseline (135.765 us; speedup 1.0000x reference)
//
#include <hip/hip_runtime.h>
#include <hip/hip_fp16.h>

#define KSZ 11
#define HALO 5
#define TILE 32
#define SMW 42      /* staged cols = TILE + 2*HALO */
#define VSTR 43     /* vbuf row stride in half2 units (odd: 2-way banks max) */
#define THREADS 256

// Normalized 1-D Gaussian, sigma=1.5, K=11.
#define W0 1.0283800e-03f
#define W1 7.5987000e-03f
#define W2 3.6000800e-02f
#define W3 1.0936070e-01f
#define W4 2.1300550e-01f
#define W5 2.6601170e-01f

// V-pass-first fused SSIM: vertical blur streamed DIRECTLY from global
// (no input staging LDS), channel-packed half2 math throughout.
// Only V-results in LDS (21.5KB) -> 7 blocks/CU. H-pass is exactly 256 items.
__global__ __launch_bounds__(THREADS) void ssim_tile_kernel(
    const float* __restrict__ x, const float* __restrict__ y,
    float* __restrict__ partial, int W, int H)
{
    __shared__ __half2 vbuf[4][TILE * VSTR];   // 4 x 32 x 43 x 4B = 21.5 KB
    __shared__ float wsum[THREADS / 64];

    const float wf[KSZ] = {W0, W1, W2, W3, W4, W5, W4, W3, W2, W1, W0};
    __half2 w2[KSZ];
#pragma unroll
    for (int k = 0; k < KSZ; ++k) w2[k] = __float2half2_rn(wf[k]);
    const __half2 hz = __float2half2_rn(0.0f);

    const int tid = threadIdx.x;
    const int tilesPerRow = W / TILE;
    const int tileR = (blockIdx.x / tilesPerRow) * TILE;
    const int tileC = (blockIdx.x % tilesPerRow) * TILE;
    const size_t plane = (size_t)W * (size_t)H;
    const size_t base0 = (size_t)blockIdx.y * 2 * plane;   // channel 0
    const size_t base1 = base0 + plane;                    // channel 1

    const bool interior = (tileR >= HALO) && (tileR + TILE + HALO <= H) &&
                          (tileC >= HALO) && (tileC + TILE + HALO <= W);

    // ---- Vertical pass from GLOBAL: 336 items = rgrp(8) x col(42) ----
    // item: col c of the 42 staged cols, output rows r0..r0+3.
    // Stream a 14-row window; each value feeds <=4 accumulators then dies.
    for (int it = tid; it < SMW * 8; it += THREADS) {
        const int rg = it / SMW;          // 0..7
        const int c  = it - rg * SMW;     // 0..41  (consecutive lanes -> coalesced)
        const int r0 = rg << 2;

        __half2 a0[4] = {hz, hz, hz, hz}, a1[4] = {hz, hz, hz, hz};
        __half2 a2[4] = {hz, hz, hz, hz}, a3[4] = {hz, hz, hz, hz};

        if (interior) {
            const size_t g0 = (size_t)(tileR + r0 - HALO) * W + (tileC - HALO + c);
            const float* px0 = x + base0 + g0;
            const float* px1 = x + base1 + g0;
            const float* py0 = y + base0 + g0;
            const float* py1 = y + base1 + g0;
#pragma unroll
            for (int i = 0; i < 14; ++i) {
                const int o = i * W;
                __half2 hx = __floats2half2_rn(px0[o], px1[o]);
                __half2 hy = __floats2half2_rn(py0[o], py1[o]);
                __half2 pq = __hfma2(hy, hy, __hmul2(hx, hx));
                __half2 qq = __hmul2(hx, hy);
#pragma unroll
                for (int j = 0; j < 4; ++j) {
                    const int t = i - j;
                    if (t >= 0 && t < KSZ) {
                        a0[j] = __hfma2(w2[t], hx, a0[j]);
                        a1[j] = __hfma2(w2[t], hy, a1[j]);
                        a2[j] = __hfma2(w2[t], pq, a2[j]);
                        a3[j] = __hfma2(w2[t], qq, a3[j]);
                    }
                }
            }
        } else {
            const int col = tileC - HALO + c;
            const bool colok = (col >= 0 && col < W);
#pragma unroll
            for (int i = 0; i < 14; ++i) {
                const int row = tileR + r0 - HALO + i;
                float vx0 = 0.f, vx1 = 0.f, vy0 = 0.f, vy1 = 0.f;
                if (colok && row >= 0 && row < H) {
                    const size_t g = (size_t)row * W + col;
                    vx0 = x[base0 + g]; vx1 = x[base1 + g];
                    vy0 = y[base0 + g]; vy1 = y[base1 + g];
                }
                __half2 hx = __floats2half2_rn(vx0, vx1);
                __half2 hy = __floats2half2_rn(vy0, vy1);
                __half2 pq = __hfma2(hy, hy, __hmul2(hx, hx));
                __half2 qq = __hmul2(hx, hy);
#pragma unroll
                for (int j = 0; j < 4; ++j) {
                    const int t = i - j;
                    if (t >= 0 && t < KSZ) {
                        a0[j] = __hfma2(w2[t], hx, a0[j]);
                        a1[j] = __hfma2(w2[t], hy, a1[j]);
                        a2[j] = __hfma2(w2[t], pq, a2[j]);
                        a3[j] = __hfma2(w2[t], qq, a3[j]);
                    }
                }
            }
        }

        const int ob = r0 * VSTR + c;
#pragma unroll
        for (int j = 0; j < 4; ++j) {
            vbuf[0][ob + j * VSTR] = a0[j];
            vbuf[1][ob + j * VSTR] = a1[j];
            vbuf[2][ob + j * VSTR] = a2[j];
            vbuf[3][ob + j * VSTR] = a3[j];
        }
    }
    __syncthreads();

    // ---- Horizontal pass: EXACTLY 256 items (row r, cols c0..c0+3) ----
    float bsum = 0.f;
    {
        const int r = tid >> 3;
        const int c0 = (tid & 7) << 2;
        const int rb = r * VSTR + c0;

        __half2 b0[4] = {hz, hz, hz, hz}, b1[4] = {hz, hz, hz, hz};
        __half2 b2[4] = {hz, hz, hz, hz}, b3[4] = {hz, hz, hz, hz};
#pragma unroll
        for (int k = 0; k < 14; ++k) {
            __half2 u0 = vbuf[0][rb + k];
            __half2 u1 = vbuf[1][rb + k];
            __half2 u2 = vbuf[2][rb + k];
            __half2 u3 = vbuf[3][rb + k];
#pragma unroll
            for (int j = 0; j < 4; ++j) {
                const int t = k - j;
                if (t >= 0 && t < KSZ) {
                    b0[j] = __hfma2(w2[t], u0, b0[j]);
                    b1[j] = __hfma2(w2[t], u1, b1[j]);
                    b2[j] = __hfma2(w2[t], u2, b2[j]);
                    b3[j] = __hfma2(w2[t], u3, b3[j]);
                }
            }
        }

        // ---- SSIM map (f32, per channel) ----
        const float c1 = 0.01f * 0.01f;
        const float c2 = 0.03f * 0.03f;
#pragma unroll
        for (int j = 0; j < 4; ++j) {
            float2 ux2 = __half22float2(b0[j]);
            float2 uy2 = __half22float2(b1[j]);
            float2 up2 = __half22float2(b2[j]);
            float2 uq2 = __half22float2(b3[j]);
#pragma unroll
            for (int ch = 0; ch < 2; ++ch) {
                float ux = ch ? ux2.y : ux2.x;
                float uy = ch ? uy2.y : uy2.x;
                float up = ch ? up2.y : up2.x;
                float uq = ch ? uq2.y : uq2.x;
                float sumsq = ux * ux + uy * uy;
                float vsum = up - sumsq;             // vx + vy
                float vxy = uq - ux * uy;
                float num = (2.f * ux * uy + c1) * (2.f * vxy + c2);
                float den = (sumsq + c1) * (vsum + c2);
                bsum += num * __builtin_amdgcn_rcpf(den + 1e-12f);
            }
        }
    }

    // ---- Wave shuffle reduce, cross-wave via LDS ----
#pragma unroll
    for (int off = 32; off > 0; off >>= 1) bsum += __shfl_down(bsum, off, 64);
    const int lane = tid & 63, wid = tid >> 6;
    if (lane == 0) wsum[wid] = bsum;
    __syncthreads();
    if (tid == 0) {
        float tot = 0.f;
#pragma unroll
        for (int i = 0; i < THREADS / 64; ++i) tot += wsum[i];
        partial[(size_t)blockIdx.y * gridDim.x + blockIdx.x] = tot;
    }
}

// Final deterministic reduction: n partials -> out[0] = 1 - sum/count
__global__ __launch_bounds__(256) void ssim_reduce_kernel(
    const float* __restrict__ partial, int n, float* __restrict__ out,
    double inv_count)
{
    __shared__ double ws[4];
    double s = 0.0;
    for (int i = threadIdx.x; i < n; i += 256) s += (double)partial[i];
#pragma unroll
    for (int off = 32; off > 0; off >>= 1) s += __shfl_down(s, off, 64);
    int lane = threadIdx.x & 63, wid = threadIdx.x >> 6;
    if (lane == 0) ws[wid] = s;
    __syncthreads();
    if (threadIdx.x == 0) {
        double tot = ws[0] + ws[1] + ws[2] + ws[3];
        out[0] = (float)(1.0 - tot * inv_count);
    }
}

extern "C" void kernel_launch(void* const* d_in, const int* in_sizes, int n_in,
                              void* d_out, int out_size, void* d_ws, size_t ws_size,
                              hipStream_t stream) {
    const float* x = (const float*)d_in[0];
    const float* y = (const float*)d_in[1];
    float* partial = (float*)d_ws;

    const int W = 512, H = 512;
    const int N = 32, C = 2;
    const int tilesPerPlane = (W / TILE) * (H / TILE); // 256
    // grid.y = N (batch); both channels packed per block.

    dim3 grid(tilesPerPlane, N);
    ssim_tile_kernel<<<grid, THREADS, 0, stream>>>(x, y, partial, W, H);

    const int nPartial = tilesPerPlane * N; // 8192
    const double inv_count = 1.0 / ((double)N * C * W * H);
    ssim_reduce_kernel<<<1, 256, 0, stream>>>(partial, nPartial, (float*)d_out,
                                              inv_count);
}

// Round 9
// 89.037 us; speedup vs baseline: 1.5248x; 1.5248x over previous
//
#include <hip/hip_runtime.h>
#include <hip/hip_fp16.h>

#define KSZ 11
#define HALO 5
#define TW 32       /* tile width (output cols) */
#define TH 24       /* tile height (output rows) */
#define SMW 42      /* staged cols = TW + 10 */
#define SMH 34      /* staged rows = TH + 10 */
#define INSTR 43    /* input row stride, 8B units (odd -> 2-way banks) */
#define VSTR 43     /* vbuf  row stride, 16B units */
#define THREADS 256

// Normalized 1-D Gaussian, sigma=1.5, K=11.
#define W0 1.0283800e-03f
#define W1 7.5987000e-03f
#define W2 3.6000800e-02f
#define W3 1.0936070e-01f
#define W4 2.1300550e-01f
#define W5 2.6601170e-01f

struct Pix8  { __half2 hx, hy; };             // staged input pixel (2ch x,y)
struct Pix16 { __half2 s0, s1, s2, s3; };     // V-blurred 4 signals

// Stage-once + LDS-union fused SSIM:
//   stage (8B/pixel) -> V-pass from LDS (accs in regs) -> barrier ->
//   V-results overwrite the SAME LDS (16B/pixel) -> H-pass (b128 reads) ->
//   SSIM -> reduce.  LDS = 16.5KB -> 8 blocks/CU (32 waves).
__global__ __launch_bounds__(THREADS) void ssim_tile_kernel(
    const float* __restrict__ x, const float* __restrict__ y,
    float* __restrict__ partial, int W, int H)
{
    __shared__ __align__(16) unsigned char smem_raw[TH * VSTR * 16]; // 16512 B
    __shared__ float wsum[THREADS / 64];
    Pix8*  lin = (Pix8*)smem_raw;     // [SMH][INSTR], 11696 B used
    Pix16* vb  = (Pix16*)smem_raw;    // [TH][VSTR]

    const float wf[KSZ] = {W0, W1, W2, W3, W4, W5, W4, W3, W2, W1, W0};
    __half2 w2[KSZ];
#pragma unroll
    for (int k = 0; k < KSZ; ++k) w2[k] = __float2half2_rn(wf[k]);
    const __half2 hz = __float2half2_rn(0.0f);

    const int tid = threadIdx.x;
    const int tilesPerRow = W / TW;                    // 16
    const int tileR = (blockIdx.x / tilesPerRow) * TH;
    const int tileC = (blockIdx.x % tilesPerRow) * TW;
    const size_t plane = (size_t)W * (size_t)H;
    const size_t base0 = (size_t)blockIdx.y * 2 * plane;   // channel 0
    const size_t base1 = base0 + plane;                    // channel 1

    // ---- Phase 1: stage both channels of x,y (with halo) as Pix8 ----
    const bool interior = (tileR >= HALO) && (tileR + TH + HALO <= H) &&
                          (tileC >= HALO) && (tileC + TW + HALO <= W);
    if (interior) {
        const size_t org = (size_t)(tileR - HALO) * W + (tileC - HALO);
        for (int i = tid; i < SMH * SMW; i += THREADS) {
            int r = i / SMW, c = i - r * SMW;
            size_t g = org + (size_t)r * W + c;
            Pix8 p;
            p.hx = __floats2half2_rn(x[base0 + g], x[base1 + g]);
            p.hy = __floats2half2_rn(y[base0 + g], y[base1 + g]);
            lin[r * INSTR + c] = p;
        }
    } else {
        for (int i = tid; i < SMH * SMW; i += THREADS) {
            int r = i / SMW, c = i - r * SMW;
            int gr = tileR - HALO + r;
            int gc = tileC - HALO + c;
            float x0 = 0.f, x1 = 0.f, y0 = 0.f, y1 = 0.f;
            if (gr >= 0 && gr < H && gc >= 0 && gc < W) {
                size_t g = (size_t)gr * W + (size_t)gc;
                x0 = x[base0 + g]; x1 = x[base1 + g];
                y0 = y[base0 + g]; y1 = y[base1 + g];
            }
            Pix8 p;
            p.hx = __floats2half2_rn(x0, x1);
            p.hy = __floats2half2_rn(y0, y1);
            lin[r * INSTR + c] = p;
        }
    }
    __syncthreads();

    // ---- Phase 2: V-pass from LDS; 252 items = col(42) x rgrp(6) ----
    // Accumulators stay in registers across the overwrite barrier.
    __half2 a0[4] = {hz, hz, hz, hz}, a1[4] = {hz, hz, hz, hz};
    __half2 a2[4] = {hz, hz, hz, hz}, a3[4] = {hz, hz, hz, hz};
    int vc = 0, vr0 = 0;
    if (tid < 252) {
        vc = tid % SMW;            // 0..41
        vr0 = (tid / SMW) << 2;    // 0,4,...,20
        const Pix8* col = &lin[vr0 * INSTR + vc];
#pragma unroll
        for (int i = 0; i < 14; ++i) {
            Pix8 p = col[i * INSTR];
            __half2 hx = p.hx, hy = p.hy;
            __half2 pq = __hfma2(hy, hy, __hmul2(hx, hx));   // x^2+y^2
            __half2 qq = __hmul2(hx, hy);                    // x*y
#pragma unroll
            for (int j = 0; j < 4; ++j) {
                const int t = i - j;
                if (t >= 0 && t < KSZ) {
                    a0[j] = __hfma2(w2[t], hx, a0[j]);
                    a1[j] = __hfma2(w2[t], hy, a1[j]);
                    a2[j] = __hfma2(w2[t], pq, a2[j]);
                    a3[j] = __hfma2(w2[t], qq, a3[j]);
                }
            }
        }
    }
    __syncthreads();   // ALL V reads done before overwriting input buffer

    // ---- Phase 3: write V-results into the union'd buffer ----
    if (tid < 252) {
#pragma unroll
        for (int j = 0; j < 4; ++j) {
            Pix16 o;
            o.s0 = a0[j]; o.s1 = a1[j]; o.s2 = a2[j]; o.s3 = a3[j];
            vb[(vr0 + j) * VSTR + vc] = o;
        }
    }
    __syncthreads();

    // ---- Phase 4: H-pass (b128 reads) + SSIM; 192 items = row x cgrp ----
    float bsum = 0.f;
    if (tid < TH * 8) {
        const int r = tid >> 3;
        const int c0 = (tid & 7) << 2;
        const Pix16* row = &vb[r * VSTR + c0];

        __half2 b0[4] = {hz, hz, hz, hz}, b1[4] = {hz, hz, hz, hz};
        __half2 b2[4] = {hz, hz, hz, hz}, b3[4] = {hz, hz, hz, hz};
#pragma unroll
        for (int k = 0; k < 14; ++k) {
            Pix16 u = row[k];
#pragma unroll
            for (int j = 0; j < 4; ++j) {
                const int t = k - j;
                if (t >= 0 && t < KSZ) {
                    b0[j] = __hfma2(w2[t], u.s0, b0[j]);
                    b1[j] = __hfma2(w2[t], u.s1, b1[j]);
                    b2[j] = __hfma2(w2[t], u.s2, b2[j]);
                    b3[j] = __hfma2(w2[t], u.s3, b3[j]);
                }
            }
        }

        if (tileR + r < H) {   // mask rows past image bottom (last tile row)
            const float c1 = 0.01f * 0.01f;
            const float c2 = 0.03f * 0.03f;
#pragma unroll
            for (int j = 0; j < 4; ++j) {
                float2 ux2 = __half22float2(b0[j]);
                float2 uy2 = __half22float2(b1[j]);
                float2 up2 = __half22float2(b2[j]);
                float2 uq2 = __half22float2(b3[j]);
#pragma unroll
                for (int ch = 0; ch < 2; ++ch) {
                    float ux = ch ? ux2.y : ux2.x;
                    float uy = ch ? uy2.y : uy2.x;
                    float up = ch ? up2.y : up2.x;
                    float uq = ch ? uq2.y : uq2.x;
                    float sumsq = ux * ux + uy * uy;
                    float vsum = up - sumsq;             // vx + vy
                    float vxy = uq - ux * uy;
                    float num = (2.f * ux * uy + c1) * (2.f * vxy + c2);
                    float den = (sumsq + c1) * (vsum + c2);
                    bsum += num * __builtin_amdgcn_rcpf(den + 1e-12f);
                }
            }
        }
    }

    // ---- Wave shuffle reduce, cross-wave via LDS ----
#pragma unroll
    for (int off = 32; off > 0; off >>= 1) bsum += __shfl_down(bsum, off, 64);
    const int lane = tid & 63, wid = tid >> 6;
    if (lane == 0) wsum[wid] = bsum;
    __syncthreads();
    if (tid == 0) {
        float tot = 0.f;
#pragma unroll
        for (int i = 0; i < THREADS / 64; ++i) tot += wsum[i];
        partial[(size_t)blockIdx.y * gridDim.x + blockIdx.x] = tot;
    }
}

// Final deterministic reduction: n partials -> out[0] = 1 - sum/count
__global__ __launch_bounds__(256) void ssim_reduce_kernel(
    const float* __restrict__ partial, int n, float* __restrict__ out,
    double inv_count)
{
    __shared__ double ws[4];
    double s = 0.0;
    for (int i = threadIdx.x; i < n; i += 256) s += (double)partial[i];
#pragma unroll
    for (int off = 32; off > 0; off >>= 1) s += __shfl_down(s, off, 64);
    int lane = threadIdx.x & 63, wid = threadIdx.x >> 6;
    if (lane == 0) ws[wid] = s;
    __syncthreads();
    if (threadIdx.x == 0) {
        double tot = ws[0] + ws[1] + ws[2] + ws[3];
        out[0] = (float)(1.0 - tot * inv_count);
    }
}

extern "C" void kernel_launch(void* const* d_in, const int* in_sizes, int n_in,
                              void* d_out, int out_size, void* d_ws, size_t ws_size,
                              hipStream_t stream) {
    const float* x = (const float*)d_in[0];
    const float* y = (const float*)d_in[1];
    float* partial = (float*)d_ws;

    const int W = 512, H = 512;
    const int N = 32, C = 2;
    const int tilesX = W / TW;                  // 16
    const int tilesY = (H + TH - 1) / TH;       // 22
    const int tilesPerPlane = tilesX * tilesY;  // 352
    // grid.y = N (batch); both channels packed per block.

    dim3 grid(tilesPerPlane, N);
    ssim_tile_kernel<<<grid, THREADS, 0, stream>>>(x, y, partial, W, H);

    const int nPartial = tilesPerPlane * N;     // 11264
    const double inv_count = 1.0 / ((double)N * C * W * H);
    ssim_reduce_kernel<<<1, 256, 0, stream>>>(partial, nPartial, (float*)d_out,
                                              inv_count);
}